// Round 8
// baseline (660.876 us; speedup 1.0000x reference)
//
#include <hip/hip_runtime.h>
#include <hip/hip_bf16.h>

#define NVOX 200000
#define DIM 96
#define KVOL 343
#define NEDGE 3200000
#define HID 384
#define TM 32
#define SLOT_CAP 64

typedef __attribute__((ext_vector_type(8))) __bf16 bf16x8;
typedef __attribute__((ext_vector_type(4))) __bf16 bf16x4;
typedef __attribute__((ext_vector_type(4))) float f32x4;
typedef __attribute__((ext_vector_type(4))) int i32x4;

// ---------------- prep: feats->bf16 (NT), weights->bf16 transposed, zero cnt ----------------
__global__ void prep(const float* __restrict__ feats, const float* __restrict__ w1,
                     const float* __restrict__ w2, const float* __restrict__ w_dw,
                     __bf16* __restrict__ featsb, __hip_bfloat16* __restrict__ w1t,
                     __hip_bfloat16* __restrict__ w2t, __bf16* __restrict__ wdwb,
                     int* __restrict__ cnt) {
    int t = blockIdx.x * 256 + threadIdx.x;   // NVOX*DIM/4 = 4.8M exact
    f32x4 v = __builtin_nontemporal_load((const f32x4*)(feats + t * 4));
    bf16x4 o;
    o[0] = (__bf16)v.x; o[1] = (__bf16)v.y; o[2] = (__bf16)v.z; o[3] = (__bf16)v.w;
    __builtin_nontemporal_store(o, (bf16x4*)(featsb + t * 4));
    if (t < HID * DIM) {
        int n1 = t / DIM, k1 = t % DIM;
        w1t[t] = __float2bfloat16(w1[k1 * HID + n1]);
        int n2 = t / HID, k2 = t % HID;
        w2t[t] = __float2bfloat16(w2[k2 * DIM + n2]);
        if (t < KVOL * DIM) wdwb[t] = (__bf16)w_dw[t];
    }
    if (t < NVOX) cnt[t] = 0;
}

// ---------------- scatter edges into fixed-cap per-voxel slots ----------------
__global__ void scatter_slots(const i32x4* __restrict__ in4, const i32x4* __restrict__ out4,
                              const i32x4* __restrict__ k4, int* __restrict__ cnt,
                              unsigned* __restrict__ slots) {
    int t = blockIdx.x * 256 + threadIdx.x;
    if (t >= NEDGE / 8) return;               // 400,000 threads, 8 edges each
    #pragma unroll
    for (int h = 0; h < 2; ++h) {
        int idx = t * 2 + h;
        i32x4 i = __builtin_nontemporal_load(&in4[idx]);
        i32x4 o = __builtin_nontemporal_load(&out4[idx]);
        i32x4 k = __builtin_nontemporal_load(&k4[idx]);
        int d;
        d = atomicAdd(&cnt[o.x], 1);
        __builtin_nontemporal_store((unsigned)i.x | ((unsigned)k.x << 18), &slots[o.x * SLOT_CAP + d]);
        d = atomicAdd(&cnt[o.y], 1);
        __builtin_nontemporal_store((unsigned)i.y | ((unsigned)k.y << 18), &slots[o.y * SLOT_CAP + d]);
        d = atomicAdd(&cnt[o.z], 1);
        __builtin_nontemporal_store((unsigned)i.z | ((unsigned)k.z << 18), &slots[o.z * SLOT_CAP + d]);
        d = atomicAdd(&cnt[o.w], 1);
        __builtin_nontemporal_store((unsigned)i.w | ((unsigned)k.w << 18), &slots[o.w * SLOT_CAP + d]);
    }
}

// ---------------- fused gather (16 thr/voxel) + LN + MLP + residual ----------------
__global__ __launch_bounds__(512, 4) void fused_all(
    const __bf16* __restrict__ featsb, const __bf16* __restrict__ wdwb,
    const float* __restrict__ b_dw,
    const float* __restrict__ ln_w, const float* __restrict__ ln_b,
    const __hip_bfloat16* __restrict__ w1t, const float* __restrict__ b1,
    const __hip_bfloat16* __restrict__ w2t, const float* __restrict__ b2,
    const unsigned* __restrict__ slots, const int* __restrict__ cnt,
    float* __restrict__ out)
{
    __shared__ __hip_bfloat16 At[TM][104];                 //  6,656 B
    __shared__ __align__(16) char shb[TM * 392 * 2];       // 25,088 B: recsL (gather) | Ht (MLP)
    __hip_bfloat16 (*Ht)[392] = (__hip_bfloat16 (*)[392])shb;
    unsigned (*recsL)[68] = (unsigned (*)[68])shb;         // 32 x 68 x 4 = 8,704 B

    const int t   = threadIdx.x;
    const int blk = blockIdx.x;

    // ---- gather: 16 threads/voxel = 4 channel-parts x 4 edge-quarters ----
    {
        const int row  = t >> 4;        // 0..31
        const int sub  = t & 15;
        const int part = sub & 3;       // channel quarter (lane bits 0-1)
        const int q    = sub >> 2;      // edge quarter   (lane bits 2-3)
        const int c0   = part * 24;
        const int v    = blk * TM + row;

        int c = cnt[v];
        if (c > SLOT_CAP) c = SLOT_CAP;
        const unsigned* sp = slots + v * SLOT_CAP;

        // stage rec list into LDS (16 threads x uint4 = 64 slots)
        if (sub * 4 < c)
            *(uint4*)&recsL[row][sub * 4] = *(const uint4*)(sp + sub * 4);
        __syncthreads();

        float xa[24];
        #pragma unroll
        for (int j = 0; j < 24; ++j) xa[j] = 0.f;

        const __bf16* fbase = featsb + c0;
        const __bf16* wbase = wdwb + c0;
        const unsigned* rl = recsL[row];

        const int e_lo = (c * q) >> 2;
        const int e_hi = (c * (q + 1)) >> 2;

#define LDE(F, W, ee) { unsigned rr = rl[ee]; \
        const __bf16* fr = fbase + (int)(rr & 0x3FFFFu) * DIM; \
        const __bf16* wr = wbase + (int)(rr >> 18) * DIM; \
        F##0 = *(const bf16x8*)(fr);      W##0 = *(const bf16x8*)(wr); \
        F##1 = *(const bf16x8*)(fr + 8);  W##1 = *(const bf16x8*)(wr + 8); \
        F##2 = *(const bf16x8*)(fr + 16); W##2 = *(const bf16x8*)(wr + 16); }

#define ACC(F, W) { \
        _Pragma("unroll") for (int j = 0; j < 8; ++j) xa[j]      += (float)F##0[j] * (float)W##0[j]; \
        _Pragma("unroll") for (int j = 0; j < 8; ++j) xa[8 + j]  += (float)F##1[j] * (float)W##1[j]; \
        _Pragma("unroll") for (int j = 0; j < 8; ++j) xa[16 + j] += (float)F##2[j] * (float)W##2[j]; }

        // chunks of 3 edges, all loads issued before first ACC
        for (int e = e_lo; e < e_hi; e += 3) {
            int m = e_hi - e;
            bf16x8 Af0, Af1, Af2, Aw0, Aw1, Aw2;
            bf16x8 Bf0, Bf1, Bf2, Bw0, Bw1, Bw2;
            bf16x8 Cf0, Cf1, Cf2, Cw0, Cw1, Cw2;
            LDE(Af, Aw, e);
            if (m > 1) LDE(Bf, Bw, e + 1);
            if (m > 2) LDE(Cf, Cw, e + 2);
            ACC(Af, Aw);
            if (m > 1) ACC(Bf, Bw);
            if (m > 2) ACC(Cf, Cw);
        }
#undef LDE
#undef ACC

        // combine edge-quarters (lane bits 2-3)
        #pragma unroll
        for (int j = 0; j < 24; ++j) xa[j] += __shfl_xor(xa[j], 4);
        #pragma unroll
        for (int j = 0; j < 24; ++j) xa[j] += __shfl_xor(xa[j], 8);

        // + b_dw, LayerNorm stats across 4 parts (lane bits 0-1)
        float s = 0.f, s2 = 0.f;
        #pragma unroll
        for (int j = 0; j < 24; ++j) {
            float x = xa[j] + b_dw[c0 + j];
            xa[j] = x;
            s += x; s2 += x * x;
        }
        s  += __shfl_xor(s, 1);  s  += __shfl_xor(s, 2);
        s2 += __shfl_xor(s2, 1); s2 += __shfl_xor(s2, 2);
        float mean = s * (1.f / 96.f);
        float var  = s2 * (1.f / 96.f) - mean * mean;
        float rstd = rsqrtf(var + 1e-6f);

        if (q == 0) {
            #pragma unroll
            for (int jj = 0; jj < 3; ++jj) {
                bf16x8 pack;
                #pragma unroll
                for (int j = 0; j < 8; ++j) {
                    int cch = c0 + jj*8 + j;
                    float xn = (xa[jj*8+j] - mean) * rstd * ln_w[cch] + ln_b[cch];
                    pack[j] = (__bf16)xn;
                }
                *(bf16x8*)&At[row][c0 + jj*8] = pack;
            }
        }
    }
    __syncthreads();   // At ready; all recsL reads done (Ht may now overwrite)

    const int w  = t >> 6;    // 0..7
    const int l  = t & 63;
    const int lr = l & 15;
    const int lk = l >> 4;
    const int rb = w >> 2;    // row-block 0..1 (rows rb*16..+15)
    const int jg = w & 3;     // col-group 0..3

    // ---- GEMM1: [32,96] @ [96,384]; wave (rb,jg): 16 rows x 96 cols ----
    f32x4 acc[6];
    #pragma unroll
    for (int j = 0; j < 6; ++j) acc[j] = (f32x4){0.f, 0.f, 0.f, 0.f};

    #pragma unroll
    for (int kk = 0; kk < 3; ++kk) {
        bf16x8 a = *(const bf16x8*)&At[rb*16 + lr][kk*32 + lk*8];
        #pragma unroll
        for (int j = 0; j < 6; ++j) {
            int col = jg*96 + j*16 + lr;
            bf16x8 b = *(const bf16x8*)&w1t[col * DIM + kk*32 + lk*8];
            acc[j] = __builtin_amdgcn_mfma_f32_16x16x32_bf16(a, b, acc[j], 0, 0, 0);
        }
    }

    // ---- bias + exact GELU -> Ht ----
    #pragma unroll
    for (int j = 0; j < 6; ++j) {
        int col = jg*96 + j*16 + lr;
        float bb = b1[col];
        #pragma unroll
        for (int r = 0; r < 4; ++r) {
            float vv = acc[j][r] + bb;
            float ge = 0.5f * vv * (1.f + erff(vv * 0.70710678f));
            Ht[rb*16 + lk*4 + r][col] = __float2bfloat16(ge);
        }
    }
    __syncthreads();

    // ---- GEMM2: [32,384] @ [384,96]; 6 col-tiles split 2/2/1/1 over col-groups ----
    const int jt0   = (jg < 2) ? jg * 2 : jg + 2;   // 0,2,4,5
    const int ntile = (jg < 2) ? 2 : 1;

    f32x4 acc2[2];
    acc2[0] = (f32x4){0.f, 0.f, 0.f, 0.f};
    acc2[1] = (f32x4){0.f, 0.f, 0.f, 0.f};

    #pragma unroll
    for (int kk = 0; kk < 12; ++kk) {
        bf16x8 a = *(const bf16x8*)&Ht[rb*16 + lr][kk*32 + lk*8];
        for (int j = 0; j < ntile; ++j) {
            int col = (jt0 + j)*16 + lr;
            bf16x8 b = *(const bf16x8*)&w2t[col * HID + kk*32 + lk*8];
            acc2[j] = __builtin_amdgcn_mfma_f32_16x16x32_bf16(a, b, acc2[j], 0, 0, 0);
        }
    }

    // ---- epilogue: + b2 + residual (bf16 feats), NT store ----
    for (int j = 0; j < ntile; ++j) {
        int col = (jt0 + j)*16 + lr;
        float bb = b2[col];
        #pragma unroll
        for (int r = 0; r < 4; ++r) {
            int grow = blk * TM + rb*16 + lk*4 + r;
            int off = grow * DIM + col;
            float res = (float)featsb[off];
            __builtin_nontemporal_store(acc2[j][r] + bb + res, &out[off]);
        }
    }
}

extern "C" void kernel_launch(void* const* d_in, const int* in_sizes, int n_in,
                              void* d_out, int out_size, void* d_ws, size_t ws_size,
                              hipStream_t stream) {
    const float* feats = (const float*)d_in[0];
    const float* w_dw  = (const float*)d_in[1];
    const float* b_dw  = (const float*)d_in[2];
    const float* ln_w  = (const float*)d_in[3];
    const float* ln_b  = (const float*)d_in[4];
    const float* w1    = (const float*)d_in[5];
    const float* b1    = (const float*)d_in[6];
    const float* w2    = (const float*)d_in[7];
    const float* b2    = (const float*)d_in[8];
    const int* in_idx  = (const int*)d_in[9];
    const int* out_idx = (const int*)d_in[10];
    const int* k_idx   = (const int*)d_in[11];
    float* out = (float*)d_out;

    char* ws = (char*)d_ws;
    unsigned* slots = (unsigned*)ws;                               // 51,200,000
    int* cnt   = (int*)(ws + 51200000);                            //    800,000
    __hip_bfloat16* w1t = (__hip_bfloat16*)(ws + 52000000);        //     73,728
    __hip_bfloat16* w2t = (__hip_bfloat16*)(ws + 52073728);        //     73,728
    __bf16* wdwb = (__bf16*)(ws + 52147456);                       //     65,856
    __bf16* featsb = (__bf16*)(ws + 52213312);                     // 38,400,000

    prep<<<(NVOX * DIM / 4) / 256, 256, 0, stream>>>(feats, w1, w2, w_dw,
                                                     featsb, w1t, w2t, wdwb, cnt);
    scatter_slots<<<(NEDGE / 8 + 255) / 256, 256, 0, stream>>>((const i32x4*)in_idx,
                                                               (const i32x4*)out_idx,
                                                               (const i32x4*)k_idx, cnt, slots);
    fused_all<<<NVOX / TM, 512, 0, stream>>>(featsb, wdwb, b_dw, ln_w, ln_b,
                                             w1t, b1, w2t, b2, slots, cnt, out);
}

// Round 9
// 544.966 us; speedup vs baseline: 1.2127x; 1.2127x over previous
//
#include <hip/hip_runtime.h>
#include <hip/hip_bf16.h>

#define NVOX 200000
#define DIM 96
#define KVOL 343
#define NEDGE 3200000
#define HID 384
#define TM 32
#define SLOT_CAP 64

typedef __attribute__((ext_vector_type(8))) __bf16 bf16x8;
typedef __attribute__((ext_vector_type(4))) __bf16 bf16x4;
typedef __attribute__((ext_vector_type(4))) float f32x4;
typedef __attribute__((ext_vector_type(4))) int i32x4;

// ---------------- zero cnt ----------------
__global__ void zero_cnt(int* __restrict__ cnt) {
    int i = blockIdx.x * 256 + threadIdx.x;
    if (i < NVOX) cnt[i] = 0;
}

// ---------------- fused prep + scatter ----------------
// grid covers NVOX*DIM/4 threads for feats conversion; first NEDGE/4 threads
// additionally scatter 4 edges each (traffic overlaps with streaming conv).
__global__ void prep_scatter(const float* __restrict__ feats, const float* __restrict__ w1,
                             const float* __restrict__ w2, const float* __restrict__ w_dw,
                             __bf16* __restrict__ featsb, __hip_bfloat16* __restrict__ w1t,
                             __hip_bfloat16* __restrict__ w2t, __bf16* __restrict__ wdwb,
                             const i32x4* __restrict__ in4, const i32x4* __restrict__ out4,
                             const i32x4* __restrict__ k4, int* __restrict__ cnt,
                             unsigned* __restrict__ slots) {
    int t = blockIdx.x * 256 + threadIdx.x;   // NVOX*DIM/4 = 4.8M exact
    f32x4 v = __builtin_nontemporal_load((const f32x4*)(feats + t * 4));
    bf16x4 o;
    o[0] = (__bf16)v.x; o[1] = (__bf16)v.y; o[2] = (__bf16)v.z; o[3] = (__bf16)v.w;
    __builtin_nontemporal_store(o, (bf16x4*)(featsb + t * 4));
    if (t < HID * DIM) {
        int n1 = t / DIM, k1 = t % DIM;
        w1t[t] = __float2bfloat16(w1[k1 * HID + n1]);
        int n2 = t / HID, k2 = t % HID;
        w2t[t] = __float2bfloat16(w2[k2 * DIM + n2]);
        if (t < KVOL * DIM) wdwb[t] = (__bf16)w_dw[t];
    }
    if (t < NEDGE / 4) {
        i32x4 i = __builtin_nontemporal_load(&in4[t]);
        i32x4 oo = __builtin_nontemporal_load(&out4[t]);
        i32x4 k = __builtin_nontemporal_load(&k4[t]);
        int d;
        d = atomicAdd(&cnt[oo.x], 1);
        __builtin_nontemporal_store((unsigned)i.x | ((unsigned)k.x << 18), &slots[oo.x * SLOT_CAP + d]);
        d = atomicAdd(&cnt[oo.y], 1);
        __builtin_nontemporal_store((unsigned)i.y | ((unsigned)k.y << 18), &slots[oo.y * SLOT_CAP + d]);
        d = atomicAdd(&cnt[oo.z], 1);
        __builtin_nontemporal_store((unsigned)i.z | ((unsigned)k.z << 18), &slots[oo.z * SLOT_CAP + d]);
        d = atomicAdd(&cnt[oo.w], 1);
        __builtin_nontemporal_store((unsigned)i.w | ((unsigned)k.w << 18), &slots[oo.w * SLOT_CAP + d]);
    }
}

// ---------------- fused gather (8 thr/voxel, pipelined) + LN + MLP + residual ----------------
__global__ __launch_bounds__(256, 4) void fused_all(
    const __bf16* __restrict__ featsb, const __bf16* __restrict__ wdwb,
    const float* __restrict__ b_dw,
    const float* __restrict__ ln_w, const float* __restrict__ ln_b,
    const __hip_bfloat16* __restrict__ w1t, const float* __restrict__ b1,
    const __hip_bfloat16* __restrict__ w2t, const float* __restrict__ b2,
    const unsigned* __restrict__ slots, const int* __restrict__ cnt,
    float* __restrict__ out)
{
    __shared__ __hip_bfloat16 At[TM][104];                 //  6,656 B
    __shared__ __align__(16) char shb[TM * 200 * 2];       // 12,800 B: recsL (gather) | Ht half (MLP)
    __hip_bfloat16 (*Ht)[200] = (__hip_bfloat16 (*)[200])shb;
    unsigned (*recsL)[68] = (unsigned (*)[68])shb;         // 32 x 68 x 4 = 8,704 B

    const int t   = threadIdx.x;
    const int blk = blockIdx.x;

    // ---- gather: 8 threads/voxel = 4 channel-parts x 2 contiguous edge-halves ----
    {
        const int row  = t >> 3;        // 0..31
        const int sub  = t & 7;
        const int part = sub & 3;       // channel quarter
        const int half = sub >> 2;      // edge half
        const int c0   = part * 24;
        const int v    = blk * TM + row;

        int c = cnt[v];
        if (c > SLOT_CAP) c = SLOT_CAP;
        const unsigned* sp = slots + v * SLOT_CAP;

        // stage rec list into LDS (contiguous uint4 loads)
        if (sub * 4 < c)
            *(uint4*)&recsL[row][sub * 4] = *(const uint4*)(sp + sub * 4);
        if (32 + sub * 4 < c)
            *(uint4*)&recsL[row][32 + sub * 4] = *(const uint4*)(sp + 32 + sub * 4);
        __syncthreads();

        float xa[24];
        #pragma unroll
        for (int j = 0; j < 24; ++j) xa[j] = 0.f;

        const __bf16* fbase = featsb + c0;
        const __bf16* wbase = wdwb + c0;
        const unsigned* rl = recsL[row];

        const int e_lo = half ? (c >> 1) : 0;
        const int e_hi = half ? c : (c >> 1);

#define LDE(F, W, ee) { unsigned rr = rl[ee]; \
        const __bf16* fr = fbase + (int)(rr & 0x3FFFFu) * DIM; \
        const __bf16* wr = wbase + (int)(rr >> 18) * DIM; \
        F##0 = *(const bf16x8*)(fr);      W##0 = *(const bf16x8*)(wr); \
        F##1 = *(const bf16x8*)(fr + 8);  W##1 = *(const bf16x8*)(wr + 8); \
        F##2 = *(const bf16x8*)(fr + 16); W##2 = *(const bf16x8*)(wr + 16); }

#define ACC(F, W) { \
        _Pragma("unroll") for (int j = 0; j < 8; ++j) xa[j]      += (float)F##0[j] * (float)W##0[j]; \
        _Pragma("unroll") for (int j = 0; j < 8; ++j) xa[8 + j]  += (float)F##1[j] * (float)W##1[j]; \
        _Pragma("unroll") for (int j = 0; j < 8; ++j) xa[16 + j] += (float)F##2[j] * (float)W##2[j]; }

        bf16x8 Af0, Af1, Af2, Aw0, Aw1, Aw2, Bf0, Bf1, Bf2, Bw0, Bw1, Bw2;
        int e = e_lo;
        if (e + 2 <= e_hi) {
            LDE(Af, Aw, e); LDE(Bf, Bw, e + 1);
            e += 2;
            for (; e + 2 <= e_hi; e += 2) {
                bf16x8 Cf0, Cf1, Cf2, Cw0, Cw1, Cw2, Df0, Df1, Df2, Dw0, Dw1, Dw2;
                LDE(Cf, Cw, e); LDE(Df, Dw, e + 1);     // issue next pair
                ACC(Af, Aw); ACC(Bf, Bw);               // consume current pair
                Af0 = Cf0; Af1 = Cf1; Af2 = Cf2; Aw0 = Cw0; Aw1 = Cw1; Aw2 = Cw2;
                Bf0 = Df0; Bf1 = Df1; Bf2 = Df2; Bw0 = Dw0; Bw1 = Dw1; Bw2 = Dw2;
            }
            ACC(Af, Aw); ACC(Bf, Bw);
        }
        if (e < e_hi) {
            LDE(Af, Aw, e);
            ACC(Af, Aw);
        }
#undef LDE
#undef ACC

        // combine edge-halves (lanes differing in bit 2)
        #pragma unroll
        for (int j = 0; j < 24; ++j) xa[j] += __shfl_xor(xa[j], 4);

        // + b_dw, LayerNorm stats across 4 parts
        float s = 0.f, s2 = 0.f;
        #pragma unroll
        for (int j = 0; j < 24; ++j) {
            float x = xa[j] + b_dw[c0 + j];
            xa[j] = x;
            s += x; s2 += x * x;
        }
        s  += __shfl_xor(s, 1);  s  += __shfl_xor(s, 2);
        s2 += __shfl_xor(s2, 1); s2 += __shfl_xor(s2, 2);
        float mean = s * (1.f / 96.f);
        float var  = s2 * (1.f / 96.f) - mean * mean;
        float rstd = rsqrtf(var + 1e-6f);

        if (half == 0) {
            #pragma unroll
            for (int jj = 0; jj < 3; ++jj) {
                bf16x8 pack;
                #pragma unroll
                for (int j = 0; j < 8; ++j) {
                    int cch = c0 + jj*8 + j;
                    float xn = (xa[jj*8+j] - mean) * rstd * ln_w[cch] + ln_b[cch];
                    pack[j] = (__bf16)xn;
                }
                *(bf16x8*)&At[row][c0 + jj*8] = pack;
            }
        }
    }
    __syncthreads();   // At ready; all recsL reads done (Ht may now overwrite)

    const int w  = t >> 6;
    const int l  = t & 63;
    const int lr = l & 15;
    const int lk = l >> 4;
    const int rb = w >> 1;    // row-block: rows rb*16..+15
    const int jh = w & 1;     // col-half within current 192-col slab

    f32x4 acc2[3];
    #pragma unroll
    for (int j = 0; j < 3; ++j) acc2[j] = (f32x4){0.f, 0.f, 0.f, 0.f};

    #pragma unroll
    for (int h = 0; h < 2; ++h) {
        // ---- GEMM1 half: [32,96] @ [96,192]; wave (rb,jh): 16 rows x 96 cols ----
        f32x4 acc[6];
        #pragma unroll
        for (int j = 0; j < 6; ++j) acc[j] = (f32x4){0.f, 0.f, 0.f, 0.f};

        #pragma unroll
        for (int kk = 0; kk < 3; ++kk) {
            bf16x8 a = *(const bf16x8*)&At[rb*16 + lr][kk*32 + lk*8];
            #pragma unroll
            for (int j = 0; j < 6; ++j) {
                int col = h*192 + jh*96 + j*16 + lr;
                bf16x8 b = *(const bf16x8*)&w1t[col * DIM + kk*32 + lk*8];
                acc[j] = __builtin_amdgcn_mfma_f32_16x16x32_bf16(a, b, acc[j], 0, 0, 0);
            }
        }

        if (h == 1) __syncthreads();   // GEMM2 pass 0 finished reading Ht

        // ---- bias + exact GELU -> Ht half ----
        #pragma unroll
        for (int j = 0; j < 6; ++j) {
            int col = h*192 + jh*96 + j*16 + lr;
            float bb = b1[col];
            #pragma unroll
            for (int r = 0; r < 4; ++r) {
                float vv = acc[j][r] + bb;
                float ge = 0.5f * vv * (1.f + erff(vv * 0.70710678f));
                Ht[rb*16 + lk*4 + r][jh*96 + j*16 + lr] = __float2bfloat16(ge);
            }
        }
        __syncthreads();

        // ---- GEMM2 partial: [32,192] @ [192,96]; wave (rb,jh): 16 rows x 48 cols ----
        #pragma unroll
        for (int kk = 0; kk < 6; ++kk) {
            bf16x8 a = *(const bf16x8*)&Ht[rb*16 + lr][kk*32 + lk*8];
            #pragma unroll
            for (int j = 0; j < 3; ++j) {
                int col = jh*48 + j*16 + lr;
                bf16x8 b = *(const bf16x8*)&w2t[col * HID + (h*6 + kk)*32 + lk*8];
                acc2[j] = __builtin_amdgcn_mfma_f32_16x16x32_bf16(a, b, acc2[j], 0, 0, 0);
            }
        }
    }

    // ---- epilogue: + b2 + residual (bf16 feats), NT store ----
    #pragma unroll
    for (int j = 0; j < 3; ++j) {
        int col = jh*48 + j*16 + lr;
        float bb = b2[col];
        #pragma unroll
        for (int r = 0; r < 4; ++r) {
            int grow = blk * TM + rb*16 + lk*4 + r;
            int off = grow * DIM + col;
            float res = (float)featsb[off];
            __builtin_nontemporal_store(acc2[j][r] + bb + res, &out[off]);
        }
    }
}

extern "C" void kernel_launch(void* const* d_in, const int* in_sizes, int n_in,
                              void* d_out, int out_size, void* d_ws, size_t ws_size,
                              hipStream_t stream) {
    const float* feats = (const float*)d_in[0];
    const float* w_dw  = (const float*)d_in[1];
    const float* b_dw  = (const float*)d_in[2];
    const float* ln_w  = (const float*)d_in[3];
    const float* ln_b  = (const float*)d_in[4];
    const float* w1    = (const float*)d_in[5];
    const float* b1    = (const float*)d_in[6];
    const float* w2    = (const float*)d_in[7];
    const float* b2    = (const float*)d_in[8];
    const int* in_idx  = (const int*)d_in[9];
    const int* out_idx = (const int*)d_in[10];
    const int* k_idx   = (const int*)d_in[11];
    float* out = (float*)d_out;

    char* ws = (char*)d_ws;
    unsigned* slots = (unsigned*)ws;                               // 51,200,000
    int* cnt   = (int*)(ws + 51200000);                            //    800,000
    __hip_bfloat16* w1t = (__hip_bfloat16*)(ws + 52000000);        //     73,728
    __hip_bfloat16* w2t = (__hip_bfloat16*)(ws + 52073728);        //     73,728
    __bf16* wdwb = (__bf16*)(ws + 52147456);                       //     65,856
    __bf16* featsb = (__bf16*)(ws + 52213312);                     // 38,400,000

    zero_cnt<<<(NVOX + 255) / 256, 256, 0, stream>>>(cnt);
    prep_scatter<<<(NVOX * DIM / 4) / 256, 256, 0, stream>>>(
        feats, w1, w2, w_dw, featsb, w1t, w2t, wdwb,
        (const i32x4*)in_idx, (const i32x4*)out_idx, (const i32x4*)k_idx, cnt, slots);
    fused_all<<<NVOX / TM, 256, 0, stream>>>(featsb, wdwb, b_dw, ln_w, ln_b,
                                             w1t, b1, w2t, b2, slots, cnt, out);
}

// Round 10
// 477.657 us; speedup vs baseline: 1.3836x; 1.1409x over previous
//
#include <hip/hip_runtime.h>
#include <hip/hip_bf16.h>

#define NVOX 200000
#define DIM 96
#define KVOL 343
#define NEDGE 3200000
#define HID 384
#define TM 32
#define SLOT_CAP 64

typedef __attribute__((ext_vector_type(8))) __bf16 bf16x8;
typedef __attribute__((ext_vector_type(4))) __bf16 bf16x4;
typedef __attribute__((ext_vector_type(4))) float f32x4;
typedef __attribute__((ext_vector_type(4))) int i32x4;

// ---------------- prep: feats->bf16 (NT), weights->bf16 transposed, zero cnt ----------------
__global__ void prep(const float* __restrict__ feats, const float* __restrict__ w1,
                     const float* __restrict__ w2, const float* __restrict__ w_dw,
                     __bf16* __restrict__ featsb, __hip_bfloat16* __restrict__ w1t,
                     __hip_bfloat16* __restrict__ w2t, __bf16* __restrict__ wdwb,
                     int* __restrict__ cnt) {
    int t = blockIdx.x * 256 + threadIdx.x;   // NVOX*DIM/4 = 4.8M exact
    f32x4 v = __builtin_nontemporal_load((const f32x4*)(feats + t * 4));
    bf16x4 o;
    o[0] = (__bf16)v.x; o[1] = (__bf16)v.y; o[2] = (__bf16)v.z; o[3] = (__bf16)v.w;
    __builtin_nontemporal_store(o, (bf16x4*)(featsb + t * 4));
    if (t < HID * DIM) {
        int n1 = t / DIM, k1 = t % DIM;
        w1t[t] = __float2bfloat16(w1[k1 * HID + n1]);
        int n2 = t / HID, k2 = t % HID;
        w2t[t] = __float2bfloat16(w2[k2 * DIM + n2]);
        if (t < KVOL * DIM) wdwb[t] = (__bf16)w_dw[t];
    }
    if (t < NVOX) cnt[t] = 0;
}

// ---------------- scatter into TRANSPOSED slots: slots[d * NVOX + v] ----------------
// frontier of active d-planes stays L2-resident -> no write-allocate thrash
__global__ void scatter_T(const i32x4* __restrict__ in4, const i32x4* __restrict__ out4,
                          const i32x4* __restrict__ k4, int* __restrict__ cnt,
                          unsigned* __restrict__ slots) {
    int t = blockIdx.x * 256 + threadIdx.x;   // NEDGE/4 exact
    i32x4 i = __builtin_nontemporal_load(&in4[t]);
    i32x4 o = __builtin_nontemporal_load(&out4[t]);
    i32x4 k = __builtin_nontemporal_load(&k4[t]);
    int d;
    d = atomicAdd(&cnt[o.x], 1);
    if (d < SLOT_CAP) slots[d * NVOX + o.x] = (unsigned)i.x | ((unsigned)k.x << 18);
    d = atomicAdd(&cnt[o.y], 1);
    if (d < SLOT_CAP) slots[d * NVOX + o.y] = (unsigned)i.y | ((unsigned)k.y << 18);
    d = atomicAdd(&cnt[o.z], 1);
    if (d < SLOT_CAP) slots[d * NVOX + o.z] = (unsigned)i.z | ((unsigned)k.z << 18);
    d = atomicAdd(&cnt[o.w], 1);
    if (d < SLOT_CAP) slots[d * NVOX + o.w] = (unsigned)i.w | ((unsigned)k.w << 18);
}

// ---------------- fused gather (8 thr/voxel, pipelined) + LN + MLP + residual ----------------
__global__ __launch_bounds__(256, 4) void fused_all(
    const __bf16* __restrict__ featsb, const __bf16* __restrict__ wdwb,
    const float* __restrict__ b_dw,
    const float* __restrict__ ln_w, const float* __restrict__ ln_b,
    const __hip_bfloat16* __restrict__ w1t, const float* __restrict__ b1,
    const __hip_bfloat16* __restrict__ w2t, const float* __restrict__ b2,
    const unsigned* __restrict__ slots, const int* __restrict__ cnt,
    float* __restrict__ out)
{
    __shared__ __hip_bfloat16 At[TM][104];                 //  6,656 B
    __shared__ __align__(16) char shb[TM * 200 * 2];       // 12,800 B: recsL (gather) | Ht half (MLP)
    __hip_bfloat16 (*Ht)[200] = (__hip_bfloat16 (*)[200])shb;
    unsigned (*recsL)[68] = (unsigned (*)[68])shb;         // 32 x 68 x 4 = 8,704 B

    const int t   = threadIdx.x;
    const int blk = blockIdx.x;

    // ---- gather: 8 threads/voxel = 4 channel-parts x 2 contiguous edge-halves ----
    {
        const int row  = t >> 3;        // 0..31
        const int sub  = t & 7;
        const int part = sub & 3;       // channel quarter
        const int half = sub >> 2;      // edge half
        const int c0   = part * 24;
        const int v    = blk * TM + row;

        int c = cnt[v];
        if (c > SLOT_CAP) c = SLOT_CAP;

        // stage rec list into LDS from transposed slots (strided, L2-coalesced)
        for (int d = sub; d < c; d += 8)
            recsL[row][d] = slots[d * NVOX + v];
        __syncthreads();

        float xa[24];
        #pragma unroll
        for (int j = 0; j < 24; ++j) xa[j] = 0.f;

        const __bf16* fbase = featsb + c0;
        const __bf16* wbase = wdwb + c0;
        const unsigned* rl = recsL[row];

        const int e_lo = half ? (c >> 1) : 0;
        const int e_hi = half ? c : (c >> 1);

#define LDE(F, W, ee) { unsigned rr = rl[ee]; \
        const __bf16* fr = fbase + (int)(rr & 0x3FFFFu) * DIM; \
        const __bf16* wr = wbase + (int)(rr >> 18) * DIM; \
        F##0 = *(const bf16x8*)(fr);      W##0 = *(const bf16x8*)(wr); \
        F##1 = *(const bf16x8*)(fr + 8);  W##1 = *(const bf16x8*)(wr + 8); \
        F##2 = *(const bf16x8*)(fr + 16); W##2 = *(const bf16x8*)(wr + 16); }

#define ACC(F, W) { \
        _Pragma("unroll") for (int j = 0; j < 8; ++j) xa[j]      += (float)F##0[j] * (float)W##0[j]; \
        _Pragma("unroll") for (int j = 0; j < 8; ++j) xa[8 + j]  += (float)F##1[j] * (float)W##1[j]; \
        _Pragma("unroll") for (int j = 0; j < 8; ++j) xa[16 + j] += (float)F##2[j] * (float)W##2[j]; }

        bf16x8 Af0, Af1, Af2, Aw0, Aw1, Aw2, Bf0, Bf1, Bf2, Bw0, Bw1, Bw2;
        int e = e_lo;
        if (e + 2 <= e_hi) {
            LDE(Af, Aw, e); LDE(Bf, Bw, e + 1);
            e += 2;
            for (; e + 2 <= e_hi; e += 2) {
                bf16x8 Cf0, Cf1, Cf2, Cw0, Cw1, Cw2, Df0, Df1, Df2, Dw0, Dw1, Dw2;
                LDE(Cf, Cw, e); LDE(Df, Dw, e + 1);     // issue next pair
                ACC(Af, Aw); ACC(Bf, Bw);               // consume current pair
                Af0 = Cf0; Af1 = Cf1; Af2 = Cf2; Aw0 = Cw0; Aw1 = Cw1; Aw2 = Cw2;
                Bf0 = Df0; Bf1 = Df1; Bf2 = Df2; Bw0 = Dw0; Bw1 = Dw1; Bw2 = Dw2;
            }
            ACC(Af, Aw); ACC(Bf, Bw);
        }
        if (e < e_hi) {
            LDE(Af, Aw, e);
            ACC(Af, Aw);
        }
#undef LDE
#undef ACC

        // combine edge-halves (lanes differing in bit 2)
        #pragma unroll
        for (int j = 0; j < 24; ++j) xa[j] += __shfl_xor(xa[j], 4);

        // + b_dw, LayerNorm stats across 4 parts
        float s = 0.f, s2 = 0.f;
        #pragma unroll
        for (int j = 0; j < 24; ++j) {
            float x = xa[j] + b_dw[c0 + j];
            xa[j] = x;
            s += x; s2 += x * x;
        }
        s  += __shfl_xor(s, 1);  s  += __shfl_xor(s, 2);
        s2 += __shfl_xor(s2, 1); s2 += __shfl_xor(s2, 2);
        float mean = s * (1.f / 96.f);
        float var  = s2 * (1.f / 96.f) - mean * mean;
        float rstd = rsqrtf(var + 1e-6f);

        if (half == 0) {
            #pragma unroll
            for (int jj = 0; jj < 3; ++jj) {
                bf16x8 pack;
                #pragma unroll
                for (int j = 0; j < 8; ++j) {
                    int cch = c0 + jj*8 + j;
                    float xn = (xa[jj*8+j] - mean) * rstd * ln_w[cch] + ln_b[cch];
                    pack[j] = (__bf16)xn;
                }
                *(bf16x8*)&At[row][c0 + jj*8] = pack;
            }
        }
    }
    __syncthreads();   // At ready; all recsL reads done (Ht may now overwrite)

    const int w  = t >> 6;
    const int l  = t & 63;
    const int lr = l & 15;
    const int lk = l >> 4;
    const int rb = w >> 1;    // row-block: rows rb*16..+15
    const int jh = w & 1;     // col-half within current 192-col slab

    f32x4 acc2[3];
    #pragma unroll
    for (int j = 0; j < 3; ++j) acc2[j] = (f32x4){0.f, 0.f, 0.f, 0.f};

    #pragma unroll
    for (int h = 0; h < 2; ++h) {
        // ---- GEMM1 half: [32,96] @ [96,192]; wave (rb,jh): 16 rows x 96 cols ----
        f32x4 acc[6];
        #pragma unroll
        for (int j = 0; j < 6; ++j) acc[j] = (f32x4){0.f, 0.f, 0.f, 0.f};

        #pragma unroll
        for (int kk = 0; kk < 3; ++kk) {
            bf16x8 a = *(const bf16x8*)&At[rb*16 + lr][kk*32 + lk*8];
            #pragma unroll
            for (int j = 0; j < 6; ++j) {
                int col = h*192 + jh*96 + j*16 + lr;
                bf16x8 b = *(const bf16x8*)&w1t[col * DIM + kk*32 + lk*8];
                acc[j] = __builtin_amdgcn_mfma_f32_16x16x32_bf16(a, b, acc[j], 0, 0, 0);
            }
        }

        if (h == 1) __syncthreads();   // GEMM2 pass 0 finished reading Ht

        // ---- bias + exact GELU -> Ht half ----
        #pragma unroll
        for (int j = 0; j < 6; ++j) {
            int col = h*192 + jh*96 + j*16 + lr;
            float bb = b1[col];
            #pragma unroll
            for (int r = 0; r < 4; ++r) {
                float vv = acc[j][r] + bb;
                float ge = 0.5f * vv * (1.f + erff(vv * 0.70710678f));
                Ht[rb*16 + lk*4 + r][jh*96 + j*16 + lr] = __float2bfloat16(ge);
            }
        }
        __syncthreads();

        // ---- GEMM2 partial: [32,192] @ [192,96]; wave (rb,jh): 16 rows x 48 cols ----
        #pragma unroll
        for (int kk = 0; kk < 6; ++kk) {
            bf16x8 a = *(const bf16x8*)&Ht[rb*16 + lr][kk*32 + lk*8];
            #pragma unroll
            for (int j = 0; j < 3; ++j) {
                int col = jh*48 + j*16 + lr;
                bf16x8 b = *(const bf16x8*)&w2t[col * HID + (h*6 + kk)*32 + lk*8];
                acc2[j] = __builtin_amdgcn_mfma_f32_16x16x32_bf16(a, b, acc2[j], 0, 0, 0);
            }
        }
    }

    // ---- epilogue: + b2 + residual (bf16 feats), NT store ----
    #pragma unroll
    for (int j = 0; j < 3; ++j) {
        int col = jh*48 + j*16 + lr;
        float bb = b2[col];
        #pragma unroll
        for (int r = 0; r < 4; ++r) {
            int grow = blk * TM + rb*16 + lk*4 + r;
            int off = grow * DIM + col;
            float res = (float)featsb[off];
            __builtin_nontemporal_store(acc2[j][r] + bb + res, &out[off]);
        }
    }
}

extern "C" void kernel_launch(void* const* d_in, const int* in_sizes, int n_in,
                              void* d_out, int out_size, void* d_ws, size_t ws_size,
                              hipStream_t stream) {
    const float* feats = (const float*)d_in[0];
    const float* w_dw  = (const float*)d_in[1];
    const float* b_dw  = (const float*)d_in[2];
    const float* ln_w  = (const float*)d_in[3];
    const float* ln_b  = (const float*)d_in[4];
    const float* w1    = (const float*)d_in[5];
    const float* b1    = (const float*)d_in[6];
    const float* w2    = (const float*)d_in[7];
    const float* b2    = (const float*)d_in[8];
    const int* in_idx  = (const int*)d_in[9];
    const int* out_idx = (const int*)d_in[10];
    const int* k_idx   = (const int*)d_in[11];
    float* out = (float*)d_out;

    char* ws = (char*)d_ws;
    unsigned* slots = (unsigned*)ws;                               // 51,200,000
    int* cnt   = (int*)(ws + 51200000);                            //    800,000
    __hip_bfloat16* w1t = (__hip_bfloat16*)(ws + 52000000);        //     73,728
    __hip_bfloat16* w2t = (__hip_bfloat16*)(ws + 52073728);        //     73,728
    __bf16* wdwb = (__bf16*)(ws + 52147456);                       //     65,856
    __bf16* featsb = (__bf16*)(ws + 52213312);                     // 38,400,000

    prep<<<(NVOX * DIM / 4) / 256, 256, 0, stream>>>(feats, w1, w2, w_dw,
                                                     featsb, w1t, w2t, wdwb, cnt);
    scatter_T<<<NEDGE / 4 / 256, 256, 0, stream>>>((const i32x4*)in_idx,
                                                   (const i32x4*)out_idx,
                                                   (const i32x4*)k_idx, cnt, slots);
    fused_all<<<NVOX / TM, 256, 0, stream>>>(featsb, wdwb, b_dw, ln_w, ln_b,
                                             w1t, b1, w2t, b2, slots, cnt, out);
}